// Round 5
// baseline (100.808 us; speedup 1.0000x reference)
//
#include <hip/hip_runtime.h>

#define G 128
#define D_OUT 16
#define BIN_SHIFT 3              // 8 cells per bin per dim
#define NBINS (16 * 16 * 16)     // 4096
#define NBLK 256                 // blocks for hist/scatter passes

typedef float f32x4 __attribute__((ext_vector_type(4)));

// ---------- shared helpers ----------

__device__ __forceinline__ void stage_grids(const float* __restrict__ xs0,
                                            const float* __restrict__ xs1,
                                            const float* __restrict__ xs2,
                                            float (*sxs)[G], int tid, int nthreads)
{
    for (int i = tid; i < 3 * G; i += nthreads) {
        float v;
        if (i < G)            v = xs0[i];
        else if (i < 2 * G)   v = xs1[i - G];
        else                  v = xs2[i - 2 * G];
        (&sxs[0][0])[i] = v;
    }
}

// largest idx with g[idx] <= clamp(v); also fractional coordinate t
__device__ __forceinline__ void search1(const float* __restrict__ g, float v,
                                        int& li, float& t)
{
    v = fminf(fmaxf(v, g[0]), g[G - 1]);
    int idx = 0;
    #pragma unroll
    for (int s = 64; s >= 1; s >>= 1) {
        int cand = idx + s;
        if (g[cand] <= v) idx = cand;
    }
    if (idx > G - 2) idx = G - 2;
    li = idx;
    t  = (v - g[idx]) / (g[idx + 1] - g[idx]);
}

__device__ __forceinline__ int bin_of(int li0, int li1, int li2)
{
    return ((li0 >> BIN_SHIFT) << 8) | ((li1 >> BIN_SHIFT) << 4) | (li2 >> BIN_SHIFT);
}

// ---------- pass 1: per-block LDS histogram, atomic-free global flush ----------

__global__ __launch_bounds__(256) void hist_kernel(
    const float* __restrict__ x,
    const float* __restrict__ xs0, const float* __restrict__ xs1, const float* __restrict__ xs2,
    unsigned int* __restrict__ counts,   // [NBLK][NBINS]
    int n, int qpb)
{
    __shared__ float sxs[3][G];
    __shared__ unsigned int hist[NBINS];
    const int tid = threadIdx.x, blk = blockIdx.x;

    stage_grids(xs0, xs1, xs2, sxs, tid, 256);
    for (int i = tid; i < NBINS; i += 256) hist[i] = 0u;
    __syncthreads();

    const int q0 = blk * qpb, q1 = min(n, q0 + qpb);
    for (int q = q0 + tid; q < q1; q += 256) {
        int li[3]; float t;
        #pragma unroll
        for (int d = 0; d < 3; ++d) search1(sxs[d], x[q * 3 + d], li[d], t);
        atomicAdd(&hist[bin_of(li[0], li[1], li[2])], 1u);   // LDS atomic
    }
    __syncthreads();

    for (int i = tid; i < NBINS; i += 256)
        counts[(size_t)blk * NBINS + i] = hist[i];           // coalesced
}

// ---------- pass 2a: per-bin exclusive scan across the 256 block-rows ----------

__global__ __launch_bounds__(256) void scan_block_kernel(
    const unsigned int* __restrict__ counts,   // [NBLK][NBINS]
    unsigned int* __restrict__ offs,           // [NBLK][NBINS] exclusive within bin
    unsigned int* __restrict__ totals)         // [NBINS]
{
    __shared__ unsigned int sd[NBLK];
    const int b = blockIdx.x, k = threadIdx.x;
    const unsigned int v = counts[(size_t)k * NBINS + b];
    sd[k] = v;
    __syncthreads();
    for (int off = 1; off < NBLK; off <<= 1) {
        unsigned int t = sd[k];
        unsigned int a = (k >= off) ? sd[k - off] : 0u;
        __syncthreads();
        sd[k] = t + a;
        __syncthreads();
    }
    const unsigned int incl = sd[k];
    offs[(size_t)k * NBINS + b] = incl - v;
    if (k == NBLK - 1) totals[b] = incl;
}

// ---------- pass 2b: exclusive scan over 4096 bin totals (single block) ----------

__global__ __launch_bounds__(1024) void scan_totals_kernel(
    const unsigned int* __restrict__ totals, unsigned int* __restrict__ bin_base)
{
    __shared__ unsigned int sd[1024];
    const int t = threadIdx.x;
    uint4 c = ((const uint4*)totals)[t];
    unsigned int s = c.x + c.y + c.z + c.w;
    sd[t] = s;
    __syncthreads();
    for (int off = 1; off < 1024; off <<= 1) {
        unsigned int v = sd[t];
        unsigned int add = (t >= off) ? sd[t - off] : 0u;
        __syncthreads();
        sd[t] = v + add;
        __syncthreads();
    }
    unsigned int excl = sd[t] - s;
    uint4 o;
    o.x = excl;
    o.y = o.x + c.x;
    o.z = o.y + c.y;
    o.w = o.z + c.z;
    ((uint4*)bin_base)[t] = o;
}

// ---------- pass 3: deterministic scatter; payload carries (t0,t1,t2,q) + cell ----------

__global__ __launch_bounds__(256) void scatter_kernel(
    const float* __restrict__ x,
    const float* __restrict__ xs0, const float* __restrict__ xs1, const float* __restrict__ xs2,
    const unsigned int* __restrict__ offs,      // [NBLK][NBINS]
    const unsigned int* __restrict__ bin_base,  // [NBINS]
    float4* __restrict__ payload,
    unsigned int* __restrict__ cells,
    int n, int qpb)
{
    __shared__ float sxs[3][G];
    __shared__ unsigned int base[NBINS];
    const int tid = threadIdx.x, blk = blockIdx.x;

    stage_grids(xs0, xs1, xs2, sxs, tid, 256);
    for (int i = tid; i < NBINS; i += 256)
        base[i] = bin_base[i] + offs[(size_t)blk * NBINS + i];
    __syncthreads();

    const int q0 = blk * qpb, q1 = min(n, q0 + qpb);
    for (int q = q0 + tid; q < q1; q += 256) {
        int li0, li1, li2; float t0, t1, t2;
        search1(sxs[0], x[q * 3 + 0], li0, t0);
        search1(sxs[1], x[q * 3 + 1], li1, t1);
        search1(sxs[2], x[q * 3 + 2], li2, t2);
        unsigned int slot = atomicAdd(&base[bin_of(li0, li1, li2)], 1u);  // LDS atomic
        payload[slot] = make_float4(t0, t1, t2, __uint_as_float((unsigned int)q));
        cells[slot]   = ((unsigned int)li0 << 14) | ((unsigned int)li1 << 7) | (unsigned int)li2;
    }
}

// ---------- pass 4: pure gather+FMA over the bin-sorted stream ----------

__global__ __launch_bounds__(256) void interp_gather_kernel(
    const float4* __restrict__ payload,
    const unsigned int* __restrict__ cells,
    const float* __restrict__ y,
    float* __restrict__ out, int n)
{
    // XCD-aware swizzle: consecutive sorted chunks stay on one XCD's L2.
    int bid = blockIdx.x;
    int nb  = gridDim.x;
    if ((nb & 7) == 0) {
        int chunk = nb >> 3;
        bid = (bid & 7) * chunk + (bid >> 3);
    }

    const int i = bid * 64 + (threadIdx.x >> 2);
    if (i >= n) return;
    const int cg = (threadIdx.x & 3) * 4;

    const float4 p = payload[i];
    const unsigned int cell = cells[i];
    const unsigned int q = __float_as_uint(p.w);

    const float t0 = p.x, t1 = p.y, t2 = p.z;
    const float u0 = 1.f - t0, u1 = 1.f - t1, u2 = 1.f - t2;

    const float* yb = y + (size_t)cell * D_OUT + cg;
    // float-offsets for corner steps: e0 -> +G*G*D_OUT, e1 -> +G*D_OUT, e2 -> +D_OUT
    const f32x4 v000 = *(const f32x4*)(yb);
    const f32x4 v001 = *(const f32x4*)(yb + D_OUT);
    const f32x4 v010 = *(const f32x4*)(yb + G * D_OUT);
    const f32x4 v011 = *(const f32x4*)(yb + G * D_OUT + D_OUT);
    const f32x4 v100 = *(const f32x4*)(yb + G * G * D_OUT);
    const f32x4 v101 = *(const f32x4*)(yb + G * G * D_OUT + D_OUT);
    const f32x4 v110 = *(const f32x4*)(yb + G * G * D_OUT + G * D_OUT);
    const f32x4 v111 = *(const f32x4*)(yb + G * G * D_OUT + G * D_OUT + D_OUT);

    const float w000 = u0 * u1 * u2, w001 = u0 * u1 * t2;
    const float w010 = u0 * t1 * u2, w011 = u0 * t1 * t2;
    const float w100 = t0 * u1 * u2, w101 = t0 * u1 * t2;
    const float w110 = t0 * t1 * u2, w111 = t0 * t1 * t2;

    f32x4 acc = w000 * v000 + w001 * v001 + w010 * v010 + w011 * v011
              + w100 * v100 + w101 * v101 + w110 * v110 + w111 * v111;

    // streaming store: don't let the 64MB output evict y from L2
    __builtin_nontemporal_store(acc, (f32x4*)(out + (size_t)q * D_OUT + cg));
}

// ---------- fallback: direct (unsorted) kernel, known-good from R1 ----------

__global__ __launch_bounds__(256) void interp3d_kernel(
    const float* __restrict__ x, const float* __restrict__ y,
    const float* __restrict__ xs0, const float* __restrict__ xs1, const float* __restrict__ xs2,
    float* __restrict__ out, int nquery)
{
    __shared__ float sxs[3][G];
    stage_grids(xs0, xs1, xs2, sxs, threadIdx.x, 256);
    __syncthreads();

    const int q = blockIdx.x * 64 + (threadIdx.x >> 2);
    if (q >= nquery) return;
    const int cg = (threadIdx.x & 3) * 4;

    int li[3]; float t[3];
    #pragma unroll
    for (int d = 0; d < 3; ++d) search1(sxs[d], x[q * 3 + d], li[d], t[d]);

    const float w0[3] = { 1.f - t[0], 1.f - t[1], 1.f - t[2] };
    const float w1[3] = { t[0], t[1], t[2] };

    float4 acc = make_float4(0.f, 0.f, 0.f, 0.f);
    #pragma unroll
    for (int e = 0; e < 8; ++e) {
        const int e0 = (e >> 2) & 1, e1 = (e >> 1) & 1, e2 = e & 1;
        const float w = (e0 ? w1[0] : w0[0]) * (e1 ? w1[1] : w0[1]) * (e2 ? w1[2] : w0[2]);
        const int idx = ((li[0] + e0) * G + (li[1] + e1)) * G + (li[2] + e2);
        const float4 v = *(const float4*)(y + (size_t)idx * D_OUT + cg);
        acc.x += w * v.x; acc.y += w * v.y; acc.z += w * v.z; acc.w += w * v.w;
    }
    *(float4*)(out + (size_t)q * D_OUT + cg) = acc;
}

extern "C" void kernel_launch(void* const* d_in, const int* in_sizes, int n_in,
                              void* d_out, int out_size, void* d_ws, size_t ws_size,
                              hipStream_t stream) {
    const float* x   = (const float*)d_in[0];
    const float* y   = (const float*)d_in[1];
    const float* xs0 = (const float*)d_in[2];
    const float* xs1 = (const float*)d_in[3];
    const float* xs2 = (const float*)d_in[4];
    float* out = (float*)d_out;

    const int nquery = in_sizes[0] / 3;

    // workspace layout
    const size_t counts_elems = (size_t)NBLK * NBINS;           // 1M uints = 4MB
    const size_t need = (2 * counts_elems + 2 * NBINS) * sizeof(unsigned int)
                      + (size_t)nquery * (sizeof(float4) + sizeof(unsigned int));
    if (ws_size < need) {
        const int blocks = (nquery + 63) / 64;
        hipLaunchKernelGGL(interp3d_kernel, dim3(blocks), dim3(256), 0, stream,
                           x, y, xs0, xs1, xs2, out, nquery);
        return;
    }

    unsigned int* counts   = (unsigned int*)d_ws;
    unsigned int* offs     = counts + counts_elems;
    unsigned int* totals   = offs + counts_elems;
    unsigned int* bin_base = totals + NBINS;
    float4*       payload  = (float4*)(bin_base + NBINS);
    unsigned int* cells    = (unsigned int*)(payload + nquery);

    const int qpb = (nquery + NBLK - 1) / NBLK;

    hipLaunchKernelGGL(hist_kernel, dim3(NBLK), dim3(256), 0, stream,
                       x, xs0, xs1, xs2, counts, nquery, qpb);
    hipLaunchKernelGGL(scan_block_kernel, dim3(NBINS), dim3(NBLK), 0, stream,
                       counts, offs, totals);
    hipLaunchKernelGGL(scan_totals_kernel, dim3(1), dim3(1024), 0, stream,
                       totals, bin_base);
    hipLaunchKernelGGL(scatter_kernel, dim3(NBLK), dim3(256), 0, stream,
                       x, xs0, xs1, xs2, offs, bin_base, payload, cells, nquery, qpb);

    const int b64 = (nquery + 63) / 64;
    hipLaunchKernelGGL(interp_gather_kernel, dim3(b64), dim3(256), 0, stream,
                       payload, cells, y, out, nquery);
}